// Round 2
// baseline (340.365 us; speedup 1.0000x reference)
//
#include <hip/hip_runtime.h>
#include <math.h>

#define DIMD 200
#define LL   256
#define ROWS 8
#define NROWG 256   // 2048 rows / 8
#define L2E  1.4426950408889634f

static __device__ __forceinline__ float fexp2(float x) {
#if __has_builtin(__builtin_amdgcn_exp2f)
    return __builtin_amdgcn_exp2f(x);
#else
    return exp2f(x);
#endif
}
static __device__ __forceinline__ float frcp(float x) {
#if __has_builtin(__builtin_amdgcn_rcpf)
    return __builtin_amdgcn_rcpf(x);
#else
    return 1.0f / x;
#endif
}

// kA: embedding gather. Writes xx row-major [2048][200] and xxT [200][2048].
__global__ __launch_bounds__(256) void kA_gather(
    const int* __restrict__ x, const float* __restrict__ emb,
    float* __restrict__ xx, float* __restrict__ xxT)
{
    const int row0 = blockIdx.x * ROWS;
    const int e = threadIdx.x;
    if (e >= DIMD) return;
    float v[ROWS];
#pragma unroll
    for (int r = 0; r < ROWS; r++) {
        int tok = x[row0 + r];
        v[r] = emb[(size_t)tok * DIMD + e];
        xx[(size_t)(row0 + r) * DIMD + e] = v[r];
    }
    float4* p = (float4*)&xxT[(size_t)e * 2048 + row0];
    p[0] = make_float4(v[0], v[1], v[2], v[3]);
    p[1] = make_float4(v[4], v[5], v[6], v[7]);
}

// kB: h = elu(xx @ Wh + b). A-operand via uniform loads from xxT (s_load path).
__global__ __launch_bounds__(256) void kB_h(
    const float* __restrict__ xxT, const float* __restrict__ Wh_w,
    const float* __restrict__ Wh_b,
    float* __restrict__ h, float* __restrict__ hT)
{
    const int row0 = blockIdx.x * ROWS;
    const int e = threadIdx.x;
    if (e >= DIMD) return;
    float acc[ROWS];
    float bias = Wh_b[e];
#pragma unroll
    for (int r = 0; r < ROWS; r++) acc[r] = bias;
#pragma unroll 4
    for (int k = 0; k < DIMD; k++) {
        const float4* ap = (const float4*)&xxT[(size_t)k * 2048 + row0];
        float4 a0 = ap[0], a1 = ap[1];
        float w = Wh_w[(size_t)k * DIMD + e];
        acc[0] = fmaf(a0.x, w, acc[0]); acc[1] = fmaf(a0.y, w, acc[1]);
        acc[2] = fmaf(a0.z, w, acc[2]); acc[3] = fmaf(a0.w, w, acc[3]);
        acc[4] = fmaf(a1.x, w, acc[4]); acc[5] = fmaf(a1.y, w, acc[5]);
        acc[6] = fmaf(a1.z, w, acc[6]); acc[7] = fmaf(a1.w, w, acc[7]);
    }
    float hv[ROWS];
#pragma unroll
    for (int r = 0; r < ROWS; r++) {
        float a = acc[r];
        hv[r] = a > 0.0f ? a : expm1f(a);
        h[(size_t)(row0 + r) * DIMD + e] = hv[r];
    }
    float4* hp = (float4*)&hT[(size_t)e * 2048 + row0];
    hp[0] = make_float4(hv[0], hv[1], hv[2], hv[3]);
    hp[1] = make_float4(hv[4], hv[5], hv[6], hv[7]);
}

// kC: h1 = h@W1, h2b = h@W2 + b; then write attT[(b*200+e)*256 + l] = (E, bias, h, F)
// E = exp2(S*h2b), F = exp2(S*h1), S = 2*log2(e)/c; bias = -1e30 where xx==1.0 (faithful mask)
__global__ __launch_bounds__(256) void kC_h12(
    const float* __restrict__ hT, const float* __restrict__ W1_w,
    const float* __restrict__ W2_w, const float* __restrict__ bvec,
    const float* __restrict__ xx, const float* __restrict__ h,
    const float* __restrict__ cptr, float4* __restrict__ attT)
{
    const int row0 = blockIdx.x * ROWS;
    const int b = row0 >> 8;
    const int l0 = row0 & 255;
    const int e = threadIdx.x;
    if (e >= DIMD) return;
    float s1[ROWS], s2[ROWS];
    float bb = bvec[e];
#pragma unroll
    for (int r = 0; r < ROWS; r++) { s1[r] = 0.0f; s2[r] = bb; }
#pragma unroll 4
    for (int k = 0; k < DIMD; k++) {
        const float4* ap = (const float4*)&hT[(size_t)k * 2048 + row0];
        float4 a0 = ap[0], a1 = ap[1];
        float w1 = W1_w[(size_t)k * DIMD + e];
        float w2 = W2_w[(size_t)k * DIMD + e];
        s1[0] = fmaf(a0.x, w1, s1[0]); s2[0] = fmaf(a0.x, w2, s2[0]);
        s1[1] = fmaf(a0.y, w1, s1[1]); s2[1] = fmaf(a0.y, w2, s2[1]);
        s1[2] = fmaf(a0.z, w1, s1[2]); s2[2] = fmaf(a0.z, w2, s2[2]);
        s1[3] = fmaf(a0.w, w1, s1[3]); s2[3] = fmaf(a0.w, w2, s2[3]);
        s1[4] = fmaf(a1.x, w1, s1[4]); s2[4] = fmaf(a1.x, w2, s2[4]);
        s1[5] = fmaf(a1.y, w1, s1[5]); s2[5] = fmaf(a1.y, w2, s2[5]);
        s1[6] = fmaf(a1.z, w1, s1[6]); s2[6] = fmaf(a1.z, w2, s2[6]);
        s1[7] = fmaf(a1.w, w1, s1[7]); s2[7] = fmaf(a1.w, w2, s2[7]);
    }
    float cval = cptr[0];
    float S = 2.0f * L2E / cval;
#pragma unroll
    for (int r = 0; r < ROWS; r++) {
        float E = fexp2(S * s2[r]);
        float F = fexp2(S * s1[r]);
        float xv = xx[(size_t)(row0 + r) * DIMD + e];
        float biasm = (xv == 1.0f) ? -1e30f : 0.0f;   // faithful float-compare mask
        float hv = h[(size_t)(row0 + r) * DIMD + e];
        attT[(size_t)(b * DIMD + e) * LL + l0 + r] = make_float4(E, biasm, hv, F);
    }
}

// k2: per-channel masked double softmax. Block = (b,e); thread t = target pos.
// p(t,m) = exp2(fma(rcp(fma(F_t,E_m,1)), -C, bias_m));  C = 2*c*log2(e)
__global__ __launch_bounds__(256) void k2_attn(
    const float4* __restrict__ attT, const float* __restrict__ cptr,
    float* __restrict__ sfwT, float* __restrict__ sbwT)
{
    const int be = blockIdx.x;
    const size_t base = (size_t)be * LL;
    const int t = threadIdx.x;
    float4 own = attT[base + t];
    const float cval = cptr[0];
    const float negC = -2.0f * cval * L2E;
    const float F = own.w;
    float sumf = 0.0f, accf = 0.0f, sumb = 0.0f, accb = 0.0f, hsum = 0.0f;
#pragma unroll 4
    for (int m = 0; m < LL; m++) {
        float4 pm = attT[base + m];           // wave-uniform -> s_load
        float r = frcp(fmaf(F, pm.x, 1.0f));
        float pf = fexp2(fmaf(r, negC, pm.y));
        float qf = (m > t) ? pf : 0.0f;
        float qb = (m < t) ? pf : 0.0f;
        sumf += qf; accf = fmaf(qf, pm.z, accf);
        sumb += qb; accb = fmaf(qb, pm.z, accb);
        hsum += pm.z;
    }
    float uni = hsum * (1.0f / LL);
    bool selfm = own.y < -1e29f;
    float sf = (selfm || sumf == 0.0f) ? uni : accf / sumf;
    float sb = (selfm || sumb == 0.0f) ? uni : accb / sumb;
    sfwT[base + t] = sf;
    sbwT[base + t] = sb;
}

// kD: gates. gf=sfw@Wf1, gb=sbw@Wf1, g2=h@Wf2+b; u = sig(g)*h + (1-sig)*s; writes uu + uuT
__global__ __launch_bounds__(256) void kD_gate(
    const float* __restrict__ hT, const float* __restrict__ sfwT,
    const float* __restrict__ sbwT, const float* __restrict__ Wf1,
    const float* __restrict__ Wf2, const float* __restrict__ Wf2_b,
    const float* __restrict__ h,
    float* __restrict__ uu, float* __restrict__ uuT)
{
    const int row0 = blockIdx.x * ROWS;
    const int b = row0 >> 8;
    const int l0 = row0 & 255;
    const int e = threadIdx.x;
    if (e >= DIMD) return;
    float gf[ROWS], gb[ROWS], g2[ROWS];
    float bias = Wf2_b[e];
#pragma unroll
    for (int r = 0; r < ROWS; r++) { gf[r] = 0.0f; gb[r] = 0.0f; g2[r] = bias; }
#pragma unroll 2
    for (int k = 0; k < DIMD; k++) {
        const float4* fp = (const float4*)&sfwT[(size_t)(b * DIMD + k) * LL + l0];
        const float4* bp = (const float4*)&sbwT[(size_t)(b * DIMD + k) * LL + l0];
        const float4* hp = (const float4*)&hT[(size_t)k * 2048 + row0];
        float4 f0 = fp[0], f1 = fp[1];
        float4 b0 = bp[0], b1 = bp[1];
        float4 h0 = hp[0], h1v = hp[1];
        float w1 = Wf1[(size_t)k * DIMD + e];
        float w2 = Wf2[(size_t)k * DIMD + e];
        gf[0] = fmaf(f0.x, w1, gf[0]); gb[0] = fmaf(b0.x, w1, gb[0]); g2[0] = fmaf(h0.x, w2, g2[0]);
        gf[1] = fmaf(f0.y, w1, gf[1]); gb[1] = fmaf(b0.y, w1, gb[1]); g2[1] = fmaf(h0.y, w2, g2[1]);
        gf[2] = fmaf(f0.z, w1, gf[2]); gb[2] = fmaf(b0.z, w1, gb[2]); g2[2] = fmaf(h0.z, w2, g2[2]);
        gf[3] = fmaf(f0.w, w1, gf[3]); gb[3] = fmaf(b0.w, w1, gb[3]); g2[3] = fmaf(h0.w, w2, g2[3]);
        gf[4] = fmaf(f1.x, w1, gf[4]); gb[4] = fmaf(b1.x, w1, gb[4]); g2[4] = fmaf(h1v.x, w2, g2[4]);
        gf[5] = fmaf(f1.y, w1, gf[5]); gb[5] = fmaf(b1.y, w1, gb[5]); g2[5] = fmaf(h1v.y, w2, g2[5]);
        gf[6] = fmaf(f1.z, w1, gf[6]); gb[6] = fmaf(b1.z, w1, gb[6]); g2[6] = fmaf(h1v.z, w2, g2[6]);
        gf[7] = fmaf(f1.w, w1, gf[7]); gb[7] = fmaf(b1.w, w1, gb[7]); g2[7] = fmaf(h1v.w, w2, g2[7]);
    }
    // per-lane own values
    float sfo[ROWS], sbo[ROWS];
    {
        const float4* so = (const float4*)&sfwT[(size_t)(b * DIMD + e) * LL + l0];
        ((float4*)sfo)[0] = so[0]; ((float4*)sfo)[1] = so[1];
        const float4* bo = (const float4*)&sbwT[(size_t)(b * DIMD + e) * LL + l0];
        ((float4*)sbo)[0] = bo[0]; ((float4*)sbo)[1] = bo[1];
    }
    float ufw[ROWS], ubw[ROWS];
#pragma unroll
    for (int r = 0; r < ROWS; r++) {
        float hv = h[(size_t)(row0 + r) * DIMD + e];
        float ff = 1.0f / (1.0f + expf(-(gf[r] + g2[r])));
        float fb = 1.0f / (1.0f + expf(-(gb[r] + g2[r])));
        ufw[r] = ff * hv + (1.0f - ff) * sfo[r];
        ubw[r] = fb * hv + (1.0f - fb) * sbo[r];
        uu[(size_t)(row0 + r) * 400 + e]       = ufw[r];
        uu[(size_t)(row0 + r) * 400 + 200 + e] = ubw[r];
    }
    float4* uf = (float4*)&uuT[(size_t)e * 2048 + row0];
    uf[0] = make_float4(ufw[0], ufw[1], ufw[2], ufw[3]);
    uf[1] = make_float4(ufw[4], ufw[5], ufw[6], ufw[7]);
    float4* ub = (float4*)&uuT[(size_t)(DIMD + e) * 2048 + row0];
    ub[0] = make_float4(ubw[0], ubw[1], ubw[2], ubw[3]);
    ub[1] = make_float4(ubw[4], ubw[5], ubw[6], ubw[7]);
}

// kE: t1 = elu(uu @ Ws1 + b1); writes t1T [400][2048]
__global__ __launch_bounds__(256) void kE_t1(
    const float* __restrict__ uuT, const float* __restrict__ Ws1_w,
    const float* __restrict__ Ws1_b, float* __restrict__ t1T)
{
    const int row0 = blockIdx.x * ROWS;
    const int c0 = threadIdx.x;
    if (c0 >= DIMD) return;
    const int col = blockIdx.y * DIMD + c0;
    float acc[ROWS];
    float bias = Ws1_b[col];
#pragma unroll
    for (int r = 0; r < ROWS; r++) acc[r] = bias;
#pragma unroll 4
    for (int k = 0; k < 400; k++) {
        const float4* ap = (const float4*)&uuT[(size_t)k * 2048 + row0];
        float4 a0 = ap[0], a1 = ap[1];
        float w = Ws1_w[(size_t)k * 400 + col];
        acc[0] = fmaf(a0.x, w, acc[0]); acc[1] = fmaf(a0.y, w, acc[1]);
        acc[2] = fmaf(a0.z, w, acc[2]); acc[3] = fmaf(a0.w, w, acc[3]);
        acc[4] = fmaf(a1.x, w, acc[4]); acc[5] = fmaf(a1.y, w, acc[5]);
        acc[6] = fmaf(a1.z, w, acc[6]); acc[7] = fmaf(a1.w, w, acc[7]);
    }
    float tv[ROWS];
#pragma unroll
    for (int r = 0; r < ROWS; r++) {
        float a = acc[r];
        tv[r] = a > 0.0f ? a : expm1f(a);
    }
    float4* tp = (float4*)&t1T[(size_t)col * 2048 + row0];
    tp[0] = make_float4(tv[0], tv[1], tv[2], tv[3]);
    tp[1] = make_float4(tv[4], tv[5], tv[6], tv[7]);
}

// kF: att_s = t1 @ Ws + b2; s_s[b,col] += sum_r uu[row,col]*att_s[row,col]
__global__ __launch_bounds__(256) void kF_pool(
    const float* __restrict__ t1T, const float* __restrict__ Ws_w,
    const float* __restrict__ Ws_b, const float* __restrict__ uu,
    float* __restrict__ s_s)
{
    const int row0 = blockIdx.x * ROWS;
    const int b = row0 >> 8;
    const int c0 = threadIdx.x;
    if (c0 >= DIMD) return;
    const int col = blockIdx.y * DIMD + c0;
    float acc[ROWS];
    float bias = Ws_b[col];
#pragma unroll
    for (int r = 0; r < ROWS; r++) acc[r] = bias;
#pragma unroll 4
    for (int k = 0; k < 400; k++) {
        const float4* ap = (const float4*)&t1T[(size_t)k * 2048 + row0];
        float4 a0 = ap[0], a1 = ap[1];
        float w = Ws_w[(size_t)k * 400 + col];
        acc[0] = fmaf(a0.x, w, acc[0]); acc[1] = fmaf(a0.y, w, acc[1]);
        acc[2] = fmaf(a0.z, w, acc[2]); acc[3] = fmaf(a0.w, w, acc[3]);
        acc[4] = fmaf(a1.x, w, acc[4]); acc[5] = fmaf(a1.y, w, acc[5]);
        acc[6] = fmaf(a1.z, w, acc[6]); acc[7] = fmaf(a1.w, w, acc[7]);
    }
    float part = 0.0f;
#pragma unroll
    for (int r = 0; r < ROWS; r++)
        part = fmaf(uu[(size_t)(row0 + r) * 400 + col], acc[r], part);
    atomicAdd(&s_s[b * 400 + col], part);
}

// k5: y = relu(s_s@F1+b)@F2+b2
__global__ __launch_bounds__(256) void k5_final(
    const float* __restrict__ s_s, const float* __restrict__ F1_w,
    const float* __restrict__ F1_b, const float* __restrict__ F2_w,
    const float* __restrict__ F2_b, float* __restrict__ y)
{
    const int b = blockIdx.x;
    const int e = threadIdx.x;
    __shared__ float red[256];
    float val = 0.0f;
    if (e < DIMD) {
        float a = F1_b[e];
        for (int k = 0; k < 400; k++)
            a = fmaf(s_s[b * 400 + k], F1_w[k * DIMD + e], a);
        a = a > 0.0f ? a : 0.0f;
        val = a * F2_w[e];
    }
    red[e] = val;
    __syncthreads();
    for (int s = 128; s > 0; s >>= 1) {
        if (e < s) red[e] += red[e + s];
        __syncthreads();
    }
    if (e == 0) y[b] = red[0] + F2_b[0];
}

extern "C" void kernel_launch(void* const* d_in, const int* in_sizes, int n_in,
                              void* d_out, int out_size, void* d_ws, size_t ws_size,
                              hipStream_t stream)
{
    const int*   x     = (const int*)  d_in[0];
    const float* emb   = (const float*)d_in[1];
    const float* Wh_w  = (const float*)d_in[2];
    const float* Wh_b  = (const float*)d_in[3];
    const float* W1_w  = (const float*)d_in[4];
    const float* W2_w  = (const float*)d_in[5];
    const float* bvec  = (const float*)d_in[6];
    const float* cptr  = (const float*)d_in[7];
    const float* Wf1_w = (const float*)d_in[8];
    const float* Wf2_w = (const float*)d_in[9];
    const float* Wf2_b = (const float*)d_in[10];
    const float* Ws1_w = (const float*)d_in[11];
    const float* Ws1_b = (const float*)d_in[12];
    const float* Ws_w  = (const float*)d_in[13];
    const float* Ws_b  = (const float*)d_in[14];
    const float* F1_w  = (const float*)d_in[15];
    const float* F1_b  = (const float*)d_in[16];
    const float* F2_w  = (const float*)d_in[17];
    const float* F2_b  = (const float*)d_in[18];
    float* out = (float*)d_out;

    char* ws = (char*)d_ws;
    float*  xx   = (float*) (ws + 0);          // 1,638,400
    float*  xxT  = (float*) (ws + 1638400);    // 1,638,400
    float*  h    = (float*) (ws + 3276800);    // 1,638,400
    float*  hT   = (float*) (ws + 4915200);    // 1,638,400
    float4* attT = (float4*)(ws + 6553600);    // 6,553,600
    float*  sfwT = (float*) (ws + 13107200);   // 1,638,400
    float*  sbwT = (float*) (ws + 14745600);   // 1,638,400
    float*  uu   = (float*) (ws + 16384000);   // 3,276,800
    float*  uuT  = (float*) (ws + 19660800);   // 3,276,800
    float*  t1T  = (float*) (ws + 22937600);   // 3,276,800
    float*  s_s  = (float*) (ws + 26214400);   // 12,800

    hipMemsetAsync(s_s, 0, 8 * 400 * sizeof(float), stream);

    hipLaunchKernelGGL(kA_gather, dim3(NROWG), dim3(256), 0, stream, x, emb, xx, xxT);
    hipLaunchKernelGGL(kB_h,      dim3(NROWG), dim3(256), 0, stream, xxT, Wh_w, Wh_b, h, hT);
    hipLaunchKernelGGL(kC_h12,    dim3(NROWG), dim3(256), 0, stream,
                       hT, W1_w, W2_w, bvec, xx, h, cptr, attT);
    hipLaunchKernelGGL(k2_attn,   dim3(8 * DIMD), dim3(256), 0, stream,
                       attT, cptr, sfwT, sbwT);
    hipLaunchKernelGGL(kD_gate,   dim3(NROWG), dim3(256), 0, stream,
                       hT, sfwT, sbwT, Wf1_w, Wf2_w, Wf2_b, h, uu, uuT);
    hipLaunchKernelGGL(kE_t1,     dim3(NROWG, 2), dim3(256), 0, stream,
                       uuT, Ws1_w, Ws1_b, t1T);
    hipLaunchKernelGGL(kF_pool,   dim3(NROWG, 2), dim3(256), 0, stream,
                       t1T, Ws_w, Ws_b, uu, s_s);
    hipLaunchKernelGGL(k5_final,  dim3(8), dim3(256), 0, stream,
                       s_s, F1_w, F1_b, F2_w, F2_b, out);
}

// Round 3
// 332.792 us; speedup vs baseline: 1.0228x; 1.0228x over previous
//
#include <hip/hip_runtime.h>
#include <math.h>

#define L2E 1.4426950408889634f

static __device__ __forceinline__ float fexp2(float x) {
#if __has_builtin(__builtin_amdgcn_exp2f)
    return __builtin_amdgcn_exp2f(x);
#else
    return exp2f(x);
#endif
}
static __device__ __forceinline__ float frcp(float x) {
#if __has_builtin(__builtin_amdgcn_rcpf)
    return __builtin_amdgcn_rcpf(x);
#else
    return 1.0f / x;
#endif
}
static __device__ __forceinline__ float fsigmoid(float x) {
    return frcp(1.0f + fexp2(-x * L2E));   // 1/(1+e^-x)
}

// ---------------------------------------------------------------------------
// kA: embedding gather -> xxT [200][2048]. unit=wave: 64 rows x 8 cols.
// grid 200 blocks x 256 (800 units)
__global__ __launch_bounds__(256) void kA_gather(
    const int* __restrict__ x, const float* __restrict__ emb,
    float* __restrict__ xxT)
{
    const int gtid = blockIdx.x * 256 + threadIdx.x;
    const int unit = gtid >> 6;
    const int lane = threadIdx.x & 63;
    const int rowblk = unit & 31;
    int c0 = (unit >> 5) * 8;
    c0 = __builtin_amdgcn_readfirstlane(c0);
    const int row = (rowblk << 6) + lane;
    const int tok = x[row];
    float4 v0 = *(const float4*)&emb[(size_t)tok * 200 + c0];
    float4 v1 = *(const float4*)&emb[(size_t)tok * 200 + c0 + 4];
    xxT[(size_t)(c0 + 0) * 2048 + row] = v0.x;
    xxT[(size_t)(c0 + 1) * 2048 + row] = v0.y;
    xxT[(size_t)(c0 + 2) * 2048 + row] = v0.z;
    xxT[(size_t)(c0 + 3) * 2048 + row] = v0.w;
    xxT[(size_t)(c0 + 4) * 2048 + row] = v1.x;
    xxT[(size_t)(c0 + 5) * 2048 + row] = v1.y;
    xxT[(size_t)(c0 + 6) * 2048 + row] = v1.z;
    xxT[(size_t)(c0 + 7) * 2048 + row] = v1.w;
}

// ---------------------------------------------------------------------------
// kB: h = elu(xx @ Wh + b) -> hT [200][2048]. lane=row, 2 cols/thread.
// grid 800 blocks (3200 units)
__global__ __launch_bounds__(256) void kB_h(
    const float* __restrict__ xxT, const float* __restrict__ Wh_w,
    const float* __restrict__ Wh_b, float* __restrict__ hT)
{
    const int gtid = blockIdx.x * 256 + threadIdx.x;
    const int unit = gtid >> 6;
    const int lane = threadIdx.x & 63;
    const int rowblk = unit & 31;
    int c0 = (unit >> 5) * 2;
    c0 = __builtin_amdgcn_readfirstlane(c0);
    const int row = (rowblk << 6) + lane;
    float a0 = Wh_b[c0], a1 = Wh_b[c0 + 1];
    const float* ap = xxT + row;
    const float* wp = Wh_w + c0;
#pragma unroll 4
    for (int k = 0; k < 200; k++) {
        float av = ap[(size_t)k * 2048];
        float2 w = *(const float2*)(wp + (size_t)k * 200);
        a0 = fmaf(av, w.x, a0);
        a1 = fmaf(av, w.y, a1);
    }
    float h0 = a0 > 0.0f ? a0 : expm1f(a0);
    float h1 = a1 > 0.0f ? a1 : expm1f(a1);
    hT[(size_t)(c0 + 0) * 2048 + row] = h0;
    hT[(size_t)(c0 + 1) * 2048 + row] = h1;
}

// ---------------------------------------------------------------------------
// kC: h1=h@W1, h2b=h@W2+b; emit attT[(b*200+e)][l] = (E, bias, h, F)
// E=exp2(S*h2b) (source m), F=exp2(S*h1) (target l), S=2*log2e/c
// grid 800 blocks (3200 units), 2 cols/thread
__global__ __launch_bounds__(256) void kC_h12(
    const float* __restrict__ hT, const float* __restrict__ W1_w,
    const float* __restrict__ W2_w, const float* __restrict__ bvec,
    const float* __restrict__ xxT, const float* __restrict__ cptr,
    float4* __restrict__ attT)
{
    const int gtid = blockIdx.x * 256 + threadIdx.x;
    const int unit = gtid >> 6;
    const int lane = threadIdx.x & 63;
    const int rowblk = unit & 31;
    int c0 = (unit >> 5) * 2;
    c0 = __builtin_amdgcn_readfirstlane(c0);
    const int row = (rowblk << 6) + lane;
    float s1_0 = 0.0f, s1_1 = 0.0f;
    float s2_0 = bvec[c0], s2_1 = bvec[c0 + 1];
    const float* ap = hT + row;
    const float* w1p = W1_w + c0;
    const float* w2p = W2_w + c0;
#pragma unroll 4
    for (int k = 0; k < 200; k++) {
        float av = ap[(size_t)k * 2048];
        float2 w1 = *(const float2*)(w1p + (size_t)k * 200);
        float2 w2 = *(const float2*)(w2p + (size_t)k * 200);
        s1_0 = fmaf(av, w1.x, s1_0); s2_0 = fmaf(av, w2.x, s2_0);
        s1_1 = fmaf(av, w1.y, s1_1); s2_1 = fmaf(av, w2.y, s2_1);
    }
    const float cval = cptr[0];
    const float S = 2.0f * L2E / cval;
    const int b = row >> 8, l = row & 255;
#pragma unroll
    for (int j = 0; j < 2; j++) {
        float s1 = j ? s1_1 : s1_0;
        float s2 = j ? s2_1 : s2_0;
        float E = fexp2(S * s2);
        float F = fexp2(S * s1);
        float xv = xxT[(size_t)(c0 + j) * 2048 + row];
        float hv = hT[(size_t)(c0 + j) * 2048 + row];
        float bias = (xv == 1.0f) ? -1e30f : 0.0f;   // faithful float-compare mask
        attT[((size_t)b * 200 + c0 + j) * 256 + l] = make_float4(E, bias, hv, F);
    }
}

// ---------------------------------------------------------------------------
// k2: per-channel masked double softmax. Block=(channel), 128 threads,
// each thread owns t and t+128. p = exp2(fma(rcp(fma(F,E,1)), -C, bias))
// grid 1600 blocks x 128
__global__ __launch_bounds__(128) void k2_attn(
    const float4* __restrict__ attT, const float* __restrict__ cptr,
    float* __restrict__ sfwT, float* __restrict__ sbwT)
{
    __shared__ float4 pk[256];
    const int ch = blockIdx.x;
    const size_t base = (size_t)ch * 256;
    const int tid = threadIdx.x;
    pk[tid] = attT[base + tid];
    pk[tid + 128] = attT[base + tid + 128];
    __syncthreads();
    const float cval = cptr[0];
    const float negC = -2.0f * cval * L2E;
    const int t0 = tid, t1 = tid + 128;
    const float4 own0 = pk[t0], own1 = pk[t1];
    const float F0 = own0.w, F1 = own1.w;
    float sb0 = 0, ab0 = 0, sf0 = 0, af0 = 0;
    float sb1 = 0, ab1 = 0, sf1 = 0, af1 = 0;
    float hsum = 0.0f;
#pragma unroll 4
    for (int m = 0; m < 256; m++) {
        float4 pm = pk[m];
        hsum += pm.z;
        float r0 = frcp(fmaf(F0, pm.x, 1.0f));
        float p0 = fexp2(fmaf(r0, negC, pm.y));
        float r1 = frcp(fmaf(F1, pm.x, 1.0f));
        float p1 = fexp2(fmaf(r1, negC, pm.y));
        float qb0 = (m < t0) ? p0 : 0.0f;
        float qf0 = (m > t0) ? p0 : 0.0f;
        float qb1 = (m < t1) ? p1 : 0.0f;
        float qf1 = (m > t1) ? p1 : 0.0f;
        sb0 += qb0; ab0 = fmaf(qb0, pm.z, ab0);
        sf0 += qf0; af0 = fmaf(qf0, pm.z, af0);
        sb1 += qb1; ab1 = fmaf(qb1, pm.z, ab1);
        sf1 += qf1; af1 = fmaf(qf1, pm.z, af1);
    }
    float uni = hsum * (1.0f / 256.0f);
    bool sm0 = own0.y < -1e29f, sm1 = own1.y < -1e29f;
    sfwT[base + t0] = (sm0 || sf0 == 0.0f) ? uni : af0 / sf0;
    sbwT[base + t0] = (sm0 || sb0 == 0.0f) ? uni : ab0 / sb0;
    sfwT[base + t1] = (sm1 || sf1 == 0.0f) ? uni : af1 / sf1;
    sbwT[base + t1] = (sm1 || sb1 == 0.0f) ? uni : ab1 / sb1;
}

// ---------------------------------------------------------------------------
// kD: gf=sfw@Wf1, gb=sbw@Wf1, g2=h@Wf2+b; u = sig(g)*h+(1-sig)*s -> uuT[400][2048]
// grid 400 blocks (1600 units), 4 cols/thread
__global__ __launch_bounds__(256) void kD_gate(
    const float* __restrict__ hT, const float* __restrict__ sfwT,
    const float* __restrict__ sbwT, const float* __restrict__ Wf1,
    const float* __restrict__ Wf2, const float* __restrict__ Wf2_b,
    float* __restrict__ uuT)
{
    const int gtid = blockIdx.x * 256 + threadIdx.x;
    const int unit = gtid >> 6;
    const int lane = threadIdx.x & 63;
    const int rowblk = unit & 31;
    int c0 = (unit >> 5) * 4;
    c0 = __builtin_amdgcn_readfirstlane(c0);
    const int row = (rowblk << 6) + lane;
    const int b = row >> 8, l = row & 255;
    float g2[4], gf[4], gb[4];
#pragma unroll
    for (int j = 0; j < 4; j++) { g2[j] = Wf2_b[c0 + j]; gf[j] = 0.0f; gb[j] = 0.0f; }
    const float* hp = hT + row;
    const float* fp = sfwT + (size_t)b * 200 * 256 + l;
    const float* bp = sbwT + (size_t)b * 200 * 256 + l;
#pragma unroll 2
    for (int k = 0; k < 200; k++) {
        float hv = hp[(size_t)k * 2048];
        float fv = fp[(size_t)k * 256];
        float bv = bp[(size_t)k * 256];
        float4 w1 = *(const float4*)(Wf1 + (size_t)k * 200 + c0);
        float4 w2 = *(const float4*)(Wf2 + (size_t)k * 200 + c0);
        g2[0] = fmaf(hv, w2.x, g2[0]); gf[0] = fmaf(fv, w1.x, gf[0]); gb[0] = fmaf(bv, w1.x, gb[0]);
        g2[1] = fmaf(hv, w2.y, g2[1]); gf[1] = fmaf(fv, w1.y, gf[1]); gb[1] = fmaf(bv, w1.y, gb[1]);
        g2[2] = fmaf(hv, w2.z, g2[2]); gf[2] = fmaf(fv, w1.z, gf[2]); gb[2] = fmaf(bv, w1.z, gb[2]);
        g2[3] = fmaf(hv, w2.w, g2[3]); gf[3] = fmaf(fv, w1.w, gf[3]); gb[3] = fmaf(bv, w1.w, gb[3]);
    }
#pragma unroll
    for (int j = 0; j < 4; j++) {
        float hv  = hT[(size_t)(c0 + j) * 2048 + row];
        float sfo = sfwT[((size_t)b * 200 + c0 + j) * 256 + l];
        float sbo = sbwT[((size_t)b * 200 + c0 + j) * 256 + l];
        float ff = fsigmoid(gf[j] + g2[j]);
        float fb = fsigmoid(gb[j] + g2[j]);
        uuT[(size_t)(c0 + j) * 2048 + row]       = ff * hv + (1.0f - ff) * sfo;
        uuT[(size_t)(200 + c0 + j) * 2048 + row] = fb * hv + (1.0f - fb) * sbo;
    }
}

// ---------------------------------------------------------------------------
// kE: t1 = elu(uu @ Ws1 + b1) -> t1T [400][2048]. grid 800 (3200 units), 4 cols
__global__ __launch_bounds__(256) void kE_t1(
    const float* __restrict__ uuT, const float* __restrict__ Ws1_w,
    const float* __restrict__ Ws1_b, float* __restrict__ t1T)
{
    const int gtid = blockIdx.x * 256 + threadIdx.x;
    const int unit = gtid >> 6;
    const int lane = threadIdx.x & 63;
    const int rowblk = unit & 31;
    int c0 = (unit >> 5) * 4;
    c0 = __builtin_amdgcn_readfirstlane(c0);
    const int row = (rowblk << 6) + lane;
    float acc[4];
#pragma unroll
    for (int j = 0; j < 4; j++) acc[j] = Ws1_b[c0 + j];
    const float* ap = uuT + row;
#pragma unroll 4
    for (int k = 0; k < 400; k++) {
        float av = ap[(size_t)k * 2048];
        float4 w = *(const float4*)(Ws1_w + (size_t)k * 400 + c0);
        acc[0] = fmaf(av, w.x, acc[0]);
        acc[1] = fmaf(av, w.y, acc[1]);
        acc[2] = fmaf(av, w.z, acc[2]);
        acc[3] = fmaf(av, w.w, acc[3]);
    }
#pragma unroll
    for (int j = 0; j < 4; j++) {
        float a = acc[j];
        t1T[(size_t)(c0 + j) * 2048 + row] = a > 0.0f ? a : expm1f(a);
    }
}

// ---------------------------------------------------------------------------
// kF: att_s = t1 @ Ws + b2; s_s[b,col] += sum_rows uu*att_s.
// grid 800 (3200 units), 4 cols; butterfly-reduce over 64 lanes then atomic
__global__ __launch_bounds__(256) void kF_pool(
    const float* __restrict__ t1T, const float* __restrict__ Ws_w,
    const float* __restrict__ Ws_b, const float* __restrict__ uuT,
    float* __restrict__ s_s)
{
    const int gtid = blockIdx.x * 256 + threadIdx.x;
    const int unit = gtid >> 6;
    const int lane = threadIdx.x & 63;
    const int rowblk = unit & 31;
    int c0 = (unit >> 5) * 4;
    c0 = __builtin_amdgcn_readfirstlane(c0);
    const int row = (rowblk << 6) + lane;
    const int b = row >> 8;
    float acc[4];
#pragma unroll
    for (int j = 0; j < 4; j++) acc[j] = Ws_b[c0 + j];
    const float* ap = t1T + row;
#pragma unroll 4
    for (int k = 0; k < 400; k++) {
        float av = ap[(size_t)k * 2048];
        float4 w = *(const float4*)(Ws_w + (size_t)k * 400 + c0);
        acc[0] = fmaf(av, w.x, acc[0]);
        acc[1] = fmaf(av, w.y, acc[1]);
        acc[2] = fmaf(av, w.z, acc[2]);
        acc[3] = fmaf(av, w.w, acc[3]);
    }
#pragma unroll
    for (int j = 0; j < 4; j++) {
        float v = acc[j] * uuT[(size_t)(c0 + j) * 2048 + row];
        for (int off = 32; off > 0; off >>= 1)
            v += __shfl_xor(v, off, 64);
        if (lane == 0) atomicAdd(&s_s[b * 400 + c0 + j], v);
    }
}

// ---------------------------------------------------------------------------
// k5: y = relu(s_s@F1+b)@F2+b2. grid 8 x 256
__global__ __launch_bounds__(256) void k5_final(
    const float* __restrict__ s_s, const float* __restrict__ F1_w,
    const float* __restrict__ F1_b, const float* __restrict__ F2_w,
    const float* __restrict__ F2_b, float* __restrict__ y)
{
    const int b = blockIdx.x;
    const int e = threadIdx.x;
    __shared__ float red[256];
    float val = 0.0f;
    if (e < 200) {
        float a = F1_b[e];
        for (int k = 0; k < 400; k++)
            a = fmaf(s_s[b * 400 + k], F1_w[k * 200 + e], a);
        a = a > 0.0f ? a : 0.0f;
        val = a * F2_w[e];
    }
    red[e] = val;
    __syncthreads();
    for (int s = 128; s > 0; s >>= 1) {
        if (e < s) red[e] += red[e + s];
        __syncthreads();
    }
    if (e == 0) y[b] = red[0] + F2_b[0];
}

extern "C" void kernel_launch(void* const* d_in, const int* in_sizes, int n_in,
                              void* d_out, int out_size, void* d_ws, size_t ws_size,
                              hipStream_t stream)
{
    const int*   x     = (const int*)  d_in[0];
    const float* emb   = (const float*)d_in[1];
    const float* Wh_w  = (const float*)d_in[2];
    const float* Wh_b  = (const float*)d_in[3];
    const float* W1_w  = (const float*)d_in[4];
    const float* W2_w  = (const float*)d_in[5];
    const float* bvec  = (const float*)d_in[6];
    const float* cptr  = (const float*)d_in[7];
    const float* Wf1_w = (const float*)d_in[8];
    const float* Wf2_w = (const float*)d_in[9];
    const float* Wf2_b = (const float*)d_in[10];
    const float* Ws1_w = (const float*)d_in[11];
    const float* Ws1_b = (const float*)d_in[12];
    const float* Ws_w  = (const float*)d_in[13];
    const float* Ws_b  = (const float*)d_in[14];
    const float* F1_w  = (const float*)d_in[15];
    const float* F1_b  = (const float*)d_in[16];
    const float* F2_w  = (const float*)d_in[17];
    const float* F2_b  = (const float*)d_in[18];
    float* out = (float*)d_out;

    char* ws = (char*)d_ws;
    float*  xxT  = (float*) (ws + 0);          // 1,638,400
    float*  hT   = (float*) (ws + 1638400);    // 1,638,400
    float4* attT = (float4*)(ws + 3276800);    // 6,553,600
    float*  sfwT = (float*) (ws + 9830400);    // 1,638,400
    float*  sbwT = (float*) (ws + 11468800);   // 1,638,400
    float*  uuT  = (float*) (ws + 13107200);   // 3,276,800
    float*  t1T  = (float*) (ws + 16384000);   // 3,276,800
    float*  s_s  = (float*) (ws + 19660800);   // 12,800

    hipMemsetAsync(s_s, 0, 8 * 400 * sizeof(float), stream);

    hipLaunchKernelGGL(kA_gather, dim3(200),  dim3(256), 0, stream, x, emb, xxT);
    hipLaunchKernelGGL(kB_h,      dim3(800),  dim3(256), 0, stream, xxT, Wh_w, Wh_b, hT);
    hipLaunchKernelGGL(kC_h12,    dim3(800),  dim3(256), 0, stream,
                       hT, W1_w, W2_w, bvec, xxT, cptr, attT);
    hipLaunchKernelGGL(k2_attn,   dim3(1600), dim3(128), 0, stream,
                       attT, cptr, sfwT, sbwT);
    hipLaunchKernelGGL(kD_gate,   dim3(400),  dim3(256), 0, stream,
                       hT, sfwT, sbwT, Wf1_w, Wf2_w, Wf2_b, uuT);
    hipLaunchKernelGGL(kE_t1,     dim3(800),  dim3(256), 0, stream,
                       uuT, Ws1_w, Ws1_b, t1T);
    hipLaunchKernelGGL(kF_pool,   dim3(800),  dim3(256), 0, stream,
                       t1T, Ws_w, Ws_b, uuT, s_s);
    hipLaunchKernelGGL(k5_final,  dim3(8),    dim3(256), 0, stream,
                       s_s, F1_w, F1_b, F2_w, F2_b, out);
}

// Round 4
// 272.994 us; speedup vs baseline: 1.2468x; 1.2190x over previous
//
#include <hip/hip_runtime.h>
#include <math.h>

#define L2E 1.4426950408889634f
#define XP  2112          // padded row stride for [chan][row] layouts (2048+64)
#define ATP 272           // attT stride in float4 (256+16)
#define SFP 320           // sfw/sbw stride in floats (256+64)

static __device__ __forceinline__ float fexp2(float x) {
#if __has_builtin(__builtin_amdgcn_exp2f)
    return __builtin_amdgcn_exp2f(x);
#else
    return exp2f(x);
#endif
}
static __device__ __forceinline__ float frcp(float x) {
#if __has_builtin(__builtin_amdgcn_rcpf)
    return __builtin_amdgcn_rcpf(x);
#else
    return 1.0f / x;
#endif
}
static __device__ __forceinline__ float fsigmoid(float x) {
    return frcp(1.0f + fexp2(-x * L2E));
}

// ---------------------------------------------------------------------------
// kA: embedding gather -> xxT [200][XP]. 200 blocks x 256 (800 waves).
// wave unit: 64 rows x 8 cols.
__global__ __launch_bounds__(256) void kA_gather(
    const int* __restrict__ x, const float* __restrict__ emb,
    float* __restrict__ xxT)
{
    const int gtid = blockIdx.x * 256 + threadIdx.x;
    const int unit = gtid >> 6;                 // 0..799
    const int lane = threadIdx.x & 63;
    const int rowblk = unit & 31;               // 32 x 64 = 2048 rows
    int c0 = (unit >> 5) * 8;                   // 25 col-groups x 8 = 200
    c0 = __builtin_amdgcn_readfirstlane(c0);
    const int row = (rowblk << 6) + lane;
    const int tok = x[row];
    float4 v0 = *(const float4*)&emb[(size_t)tok * 200 + c0];
    float4 v1 = *(const float4*)&emb[(size_t)tok * 200 + c0 + 4];
    xxT[(size_t)(c0 + 0) * XP + row] = v0.x;
    xxT[(size_t)(c0 + 1) * XP + row] = v0.y;
    xxT[(size_t)(c0 + 2) * XP + row] = v0.z;
    xxT[(size_t)(c0 + 3) * XP + row] = v0.w;
    xxT[(size_t)(c0 + 4) * XP + row] = v1.x;
    xxT[(size_t)(c0 + 5) * XP + row] = v1.y;
    xxT[(size_t)(c0 + 6) * XP + row] = v1.z;
    xxT[(size_t)(c0 + 7) * XP + row] = v1.w;
}

// ---------------------------------------------------------------------------
// kB: h = elu(xx @ Wh + b) -> hT [200][XP].
// grid (100 colpairs, 8 rowtiles) x 256. Weights staged in LDS.
__global__ __launch_bounds__(256) void kB_h(
    const float* __restrict__ xxT, const float* __restrict__ Wh_w,
    const float* __restrict__ Wh_b, float* __restrict__ hT)
{
    __shared__ float2 wl[200];
    const int c0 = blockIdx.x * 2;
    const int tid = threadIdx.x;
    const int row = blockIdx.y * 256 + tid;
    for (int i = tid; i < 200; i += 256)
        wl[i] = *(const float2*)&Wh_w[(size_t)i * 200 + c0];
    __syncthreads();
    float a0 = Wh_b[c0], a1 = Wh_b[c0 + 1];
    const float* ap = xxT + row;
#pragma unroll 8
    for (int k = 0; k < 200; k++) {
        float av = ap[(size_t)k * XP];
        float2 w = wl[k];
        a0 = fmaf(av, w.x, a0);
        a1 = fmaf(av, w.y, a1);
    }
    hT[(size_t)(c0 + 0) * XP + row] = a0 > 0.0f ? a0 : expm1f(a0);
    hT[(size_t)(c0 + 1) * XP + row] = a1 > 0.0f ? a1 : expm1f(a1);
}

// ---------------------------------------------------------------------------
// kC: h1=h@W1, h2b=h@W2+b; attT[(b*200+e)][l] = (E, D, h, F)
// E=exp2(S*h2b), F=exp2(S*h1), D = masked ? -inf : -2c*log2e
__global__ __launch_bounds__(256) void kC_h12(
    const float* __restrict__ hT, const float* __restrict__ W1_w,
    const float* __restrict__ W2_w, const float* __restrict__ bvec,
    const float* __restrict__ xxT, const float* __restrict__ cptr,
    float4* __restrict__ attT)
{
    __shared__ float2 wl1[200];
    __shared__ float2 wl2[200];
    const int c0 = blockIdx.x * 2;
    const int tid = threadIdx.x;
    const int b = blockIdx.y;
    const int row = b * 256 + tid;
    for (int i = tid; i < 200; i += 256) {
        wl1[i] = *(const float2*)&W1_w[(size_t)i * 200 + c0];
        wl2[i] = *(const float2*)&W2_w[(size_t)i * 200 + c0];
    }
    __syncthreads();
    float s1_0 = 0.0f, s1_1 = 0.0f;
    float s2_0 = bvec[c0], s2_1 = bvec[c0 + 1];
    const float* ap = hT + row;
#pragma unroll 8
    for (int k = 0; k < 200; k++) {
        float av = ap[(size_t)k * XP];
        float2 w1 = wl1[k];
        float2 w2 = wl2[k];
        s1_0 = fmaf(av, w1.x, s1_0); s2_0 = fmaf(av, w2.x, s2_0);
        s1_1 = fmaf(av, w1.y, s1_1); s2_1 = fmaf(av, w2.y, s2_1);
    }
    const float cval = cptr[0];
    const float S = 2.0f * L2E / cval;
    const float negC = -2.0f * cval * L2E;
#pragma unroll
    for (int j = 0; j < 2; j++) {
        float s1 = j ? s1_1 : s1_0;
        float s2 = j ? s2_1 : s2_0;
        float E = fexp2(S * s2);
        float F = fexp2(S * s1);
        float xv = xxT[(size_t)(c0 + j) * XP + row];
        float hv = hT[(size_t)(c0 + j) * XP + row];
        float D = (xv == 1.0f) ? -__builtin_huge_valf() : negC;  // faithful mask
        attT[(size_t)(b * 200 + c0 + j) * ATP + tid] = make_float4(E, D, hv, F);
    }
}

// ---------------------------------------------------------------------------
// k2: per-channel masked double softmax. Block = channel, thread = t.
// p(t,m) = exp2(rcp(fma(F_t,E_m,1)) * D_m);  masked m -> p = 0 exactly.
// grid 1600 x 256
__global__ __launch_bounds__(256) void k2_attn(
    const float4* __restrict__ attT,
    float* __restrict__ sfwT, float* __restrict__ sbwT)
{
    __shared__ float4 pk[256];
    const int ch = blockIdx.x;
    const int t = threadIdx.x;
    pk[t] = attT[(size_t)ch * ATP + t];
    __syncthreads();
    const float4 own = pk[t];
    const float F = own.w;
    float sumf = 0.0f, accf = 0.0f, sumb = 0.0f, accb = 0.0f, hsum = 0.0f;
#pragma unroll 8
    for (int m = 0; m < 256; m++) {
        float4 pm = pk[m];
        float r = frcp(fmaf(F, pm.x, 1.0f));
        float p = fexp2(r * pm.y);
        float qf = (m > t) ? p : 0.0f;
        float qb = (m < t) ? p : 0.0f;
        sumf += qf; accf = fmaf(qf, pm.z, accf);
        sumb += qb; accb = fmaf(qb, pm.z, accb);
        hsum += pm.z;
    }
    float uni = hsum * (1.0f / 256.0f);
    bool selfm = own.y < -3.0e38f;    // own row masked (-inf)
    sfwT[(size_t)ch * SFP + t] = (selfm || sumf == 0.0f) ? uni : accf / sumf;
    sbwT[(size_t)ch * SFP + t] = (selfm || sumb == 0.0f) ? uni : accb / sumb;
}

// ---------------------------------------------------------------------------
// kD: gf=sfw@Wf1, gb=sbw@Wf1, g2=h@Wf2+b; u = sig(g)*h+(1-sig)*s -> uuT[400][XP]
// grid (100, 8) x 256
__global__ __launch_bounds__(256) void kD_gate(
    const float* __restrict__ hT, const float* __restrict__ sfwT,
    const float* __restrict__ sbwT, const float* __restrict__ Wf1,
    const float* __restrict__ Wf2, const float* __restrict__ Wf2_b,
    float* __restrict__ uuT)
{
    __shared__ float2 wl1[200];
    __shared__ float2 wl2[200];
    const int c0 = blockIdx.x * 2;
    const int tid = threadIdx.x;
    const int b = blockIdx.y;
    const int row = b * 256 + tid;
    for (int i = tid; i < 200; i += 256) {
        wl1[i] = *(const float2*)&Wf1[(size_t)i * 200 + c0];
        wl2[i] = *(const float2*)&Wf2[(size_t)i * 200 + c0];
    }
    __syncthreads();
    float gf0 = 0, gf1 = 0, gb0 = 0, gb1 = 0;
    float g20 = Wf2_b[c0], g21 = Wf2_b[c0 + 1];
    const float* hp = hT + row;
    const float* fp = sfwT + (size_t)b * 200 * SFP + tid;
    const float* bp = sbwT + (size_t)b * 200 * SFP + tid;
#pragma unroll 4
    for (int k = 0; k < 200; k++) {
        float hv = hp[(size_t)k * XP];
        float fv = fp[(size_t)k * SFP];
        float bv = bp[(size_t)k * SFP];
        float2 w1 = wl1[k];
        float2 w2 = wl2[k];
        gf0 = fmaf(fv, w1.x, gf0); gb0 = fmaf(bv, w1.x, gb0); g20 = fmaf(hv, w2.x, g20);
        gf1 = fmaf(fv, w1.y, gf1); gb1 = fmaf(bv, w1.y, gb1); g21 = fmaf(hv, w2.y, g21);
    }
#pragma unroll
    for (int j = 0; j < 2; j++) {
        float hv  = hT[(size_t)(c0 + j) * XP + row];
        float sfo = sfwT[(size_t)(b * 200 + c0 + j) * SFP + tid];
        float sbo = sbwT[(size_t)(b * 200 + c0 + j) * SFP + tid];
        float gf = j ? gf1 : gf0, gb = j ? gb1 : gb0, g2 = j ? g21 : g20;
        float ff = fsigmoid(gf + g2);
        float fb = fsigmoid(gb + g2);
        uuT[(size_t)(c0 + j) * XP + row]       = ff * hv + (1.0f - ff) * sfo;
        uuT[(size_t)(200 + c0 + j) * XP + row] = fb * hv + (1.0f - fb) * sbo;
    }
}

// ---------------------------------------------------------------------------
// kE: t1 = elu(uu @ Ws1 + b1) -> t1T [400][XP]. grid (100, 8), 4 cols/thread
__global__ __launch_bounds__(256) void kE_t1(
    const float* __restrict__ uuT, const float* __restrict__ Ws1_w,
    const float* __restrict__ Ws1_b, float* __restrict__ t1T)
{
    __shared__ float4 wl[400];
    const int c0 = blockIdx.x * 4;
    const int tid = threadIdx.x;
    const int row = blockIdx.y * 256 + tid;
    for (int i = tid; i < 400; i += 256)
        wl[i] = *(const float4*)&Ws1_w[(size_t)i * 400 + c0];
    __syncthreads();
    float a0 = Ws1_b[c0], a1 = Ws1_b[c0 + 1], a2 = Ws1_b[c0 + 2], a3 = Ws1_b[c0 + 3];
    const float* ap = uuT + row;
#pragma unroll 8
    for (int k = 0; k < 400; k++) {
        float av = ap[(size_t)k * XP];
        float4 w = wl[k];
        a0 = fmaf(av, w.x, a0);
        a1 = fmaf(av, w.y, a1);
        a2 = fmaf(av, w.z, a2);
        a3 = fmaf(av, w.w, a3);
    }
    t1T[(size_t)(c0 + 0) * XP + row] = a0 > 0.0f ? a0 : expm1f(a0);
    t1T[(size_t)(c0 + 1) * XP + row] = a1 > 0.0f ? a1 : expm1f(a1);
    t1T[(size_t)(c0 + 2) * XP + row] = a2 > 0.0f ? a2 : expm1f(a2);
    t1T[(size_t)(c0 + 3) * XP + row] = a3 > 0.0f ? a3 : expm1f(a3);
}

// ---------------------------------------------------------------------------
// kF: att_s = t1 @ Ws + b2; s_s[b,col] += sum_rows uu*att_s. grid (100, 8)
__global__ __launch_bounds__(256) void kF_pool(
    const float* __restrict__ t1T, const float* __restrict__ Ws_w,
    const float* __restrict__ Ws_b, const float* __restrict__ uuT,
    float* __restrict__ s_s)
{
    __shared__ float4 wl[400];
    const int c0 = blockIdx.x * 4;
    const int tid = threadIdx.x;
    const int lane = tid & 63;
    const int b = blockIdx.y;
    const int row = b * 256 + tid;
    for (int i = tid; i < 400; i += 256)
        wl[i] = *(const float4*)&Ws_w[(size_t)i * 400 + c0];
    __syncthreads();
    float a0 = Ws_b[c0], a1 = Ws_b[c0 + 1], a2 = Ws_b[c0 + 2], a3 = Ws_b[c0 + 3];
    const float* ap = t1T + row;
#pragma unroll 8
    for (int k = 0; k < 400; k++) {
        float av = ap[(size_t)k * XP];
        float4 w = wl[k];
        a0 = fmaf(av, w.x, a0);
        a1 = fmaf(av, w.y, a1);
        a2 = fmaf(av, w.z, a2);
        a3 = fmaf(av, w.w, a3);
    }
    float v0 = a0 * uuT[(size_t)(c0 + 0) * XP + row];
    float v1 = a1 * uuT[(size_t)(c0 + 1) * XP + row];
    float v2 = a2 * uuT[(size_t)(c0 + 2) * XP + row];
    float v3 = a3 * uuT[(size_t)(c0 + 3) * XP + row];
#pragma unroll
    for (int off = 32; off > 0; off >>= 1) {
        v0 += __shfl_xor(v0, off, 64);
        v1 += __shfl_xor(v1, off, 64);
        v2 += __shfl_xor(v2, off, 64);
        v3 += __shfl_xor(v3, off, 64);
    }
    if (lane == 0) {
        atomicAdd(&s_s[b * 400 + c0 + 0], v0);
        atomicAdd(&s_s[b * 400 + c0 + 1], v1);
        atomicAdd(&s_s[b * 400 + c0 + 2], v2);
        atomicAdd(&s_s[b * 400 + c0 + 3], v3);
    }
}

// ---------------------------------------------------------------------------
// k5: y = relu(s_s@F1+b)@F2+b2. grid 8 x 256
__global__ __launch_bounds__(256) void k5_final(
    const float* __restrict__ s_s, const float* __restrict__ F1_w,
    const float* __restrict__ F1_b, const float* __restrict__ F2_w,
    const float* __restrict__ F2_b, float* __restrict__ y)
{
    const int b = blockIdx.x;
    const int e = threadIdx.x;
    __shared__ float red[256];
    float val = 0.0f;
    if (e < 200) {
        float a = F1_b[e];
#pragma unroll 8
        for (int k = 0; k < 400; k++)
            a = fmaf(s_s[b * 400 + k], F1_w[(size_t)k * 200 + e], a);
        a = a > 0.0f ? a : 0.0f;
        val = a * F2_w[e];
    }
    red[e] = val;
    __syncthreads();
    for (int s = 128; s > 0; s >>= 1) {
        if (e < s) red[e] += red[e + s];
        __syncthreads();
    }
    if (e == 0) y[b] = red[0] + F2_b[0];
}

extern "C" void kernel_launch(void* const* d_in, const int* in_sizes, int n_in,
                              void* d_out, int out_size, void* d_ws, size_t ws_size,
                              hipStream_t stream)
{
    const int*   x     = (const int*)  d_in[0];
    const float* emb   = (const float*)d_in[1];
    const float* Wh_w  = (const float*)d_in[2];
    const float* Wh_b  = (const float*)d_in[3];
    const float* W1_w  = (const float*)d_in[4];
    const float* W2_w  = (const float*)d_in[5];
    const float* bvec  = (const float*)d_in[6];
    const float* cptr  = (const float*)d_in[7];
    const float* Wf1_w = (const float*)d_in[8];
    const float* Wf2_w = (const float*)d_in[9];
    const float* Wf2_b = (const float*)d_in[10];
    const float* Ws1_w = (const float*)d_in[11];
    const float* Ws1_b = (const float*)d_in[12];
    const float* Ws_w  = (const float*)d_in[13];
    const float* Ws_b  = (const float*)d_in[14];
    const float* F1_w  = (const float*)d_in[15];
    const float* F1_b  = (const float*)d_in[16];
    const float* F2_w  = (const float*)d_in[17];
    const float* F2_b  = (const float*)d_in[18];
    float* out = (float*)d_out;

    char* ws = (char*)d_ws;
    float*  xxT  = (float*) (ws + 0);          // 200*2112*4 = 1,689,600
    float*  hT   = (float*) (ws + 1689600);    // 1,689,600
    float4* attT = (float4*)(ws + 3379200);    // 1600*272*16 = 6,963,200
    float*  sfwT = (float*) (ws + 10342400);   // 1600*320*4 = 2,048,000
    float*  sbwT = (float*) (ws + 12390400);   // 2,048,000
    float*  uuT  = (float*) (ws + 14438400);   // 400*2112*4 = 3,379,200
    float*  t1T  = (float*) (ws + 17817600);   // 3,379,200
    float*  s_s  = (float*) (ws + 21196800);   // 12,800

    hipMemsetAsync(s_s, 0, 8 * 400 * sizeof(float), stream);

    hipLaunchKernelGGL(kA_gather, dim3(200),      dim3(256), 0, stream, x, emb, xxT);
    hipLaunchKernelGGL(kB_h,      dim3(100, 8),   dim3(256), 0, stream, xxT, Wh_w, Wh_b, hT);
    hipLaunchKernelGGL(kC_h12,    dim3(100, 8),   dim3(256), 0, stream,
                       hT, W1_w, W2_w, bvec, xxT, cptr, attT);
    hipLaunchKernelGGL(k2_attn,   dim3(1600),     dim3(256), 0, stream,
                       attT, sfwT, sbwT);
    hipLaunchKernelGGL(kD_gate,   dim3(100, 8),   dim3(256), 0, stream,
                       hT, sfwT, sbwT, Wf1_w, Wf2_w, Wf2_b, uuT);
    hipLaunchKernelGGL(kE_t1,     dim3(100, 8),   dim3(256), 0, stream,
                       uuT, Ws1_w, Ws1_b, t1T);
    hipLaunchKernelGGL(kF_pool,   dim3(100, 8),   dim3(256), 0, stream,
                       t1T, Ws_w, Ws_b, uuT, s_s);
    hipLaunchKernelGGL(k5_final,  dim3(8),        dim3(256), 0, stream,
                       s_s, F1_w, F1_b, F2_w, F2_b, out);
}